// Round 1
// baseline (685.278 us; speedup 1.0000x reference)
//
#include <hip/hip_runtime.h>
#include <math.h>

// Problem constants
#define BB 8
#define CC 256
#define TT 8192
#define HH 4
#define DD 64
#define EPSF 1e-5f

// Kernel-1 partitioning: 512 blocks = B * 64 chunks, each covers 128 t (4 sub-chunks of 32)
#define CH1 64
#define TCHUNK (TT / CH1)      // 128
#define NSUB (TCHUNK / 32)     // 4
#define NB1 (BB * CH1)         // 512

// Workspace layout (float offsets). Total ~37 MB.
#define OFF_UPART 0
#define SZ_UPART (NB1 * HH * DD * DD)          // 512*16384 = 8388608
#define OFF_ZPART (OFF_UPART + SZ_UPART)       // 8388608
#define SZ_ZPART (NB1 * 256)                   // 131072
#define OFF_KV (OFF_ZPART + SZ_ZPART)          // 8519680
#define SZ_KV (BB * HH * DD * DD)              // 131072
#define OFF_P (OFF_KV + SZ_KV)                 // 8650752
#define SZ_P (BB * 256 * 256)                  // 524288
#define OFF_M (OFF_P + SZ_P)                   // 9175040

// ---------------------------------------------------------------------------
// Kernel 1: per (b, t-chunk): compute k_raw = Wk@x, v = Wv@x on the fly,
// accumulate partial U[h][d][e] = sum_t exp(k[d,t]+EPS) * v[e,t] and
// Z[h][d] = sum_t exp(k[d,t]+EPS). Softmax is shift-invariant so no max pass.
// Thread tid = (h = tid>>6, d = tid&63): owns k-row h*192+64+d, v-row h*192+128+d.
// ---------------------------------------------------------------------------
__global__ __launch_bounds__(256, 2) void k1_kv_partial(
    const float* __restrict__ x, const float* __restrict__ Wpre,
    float* __restrict__ ws) {
  __shared__ float xs[256 * 32];   // [c][t], stride 32 (broadcast reads only)
  __shared__ float vs[32 * 256];   // [t][row]

  const int tid = threadIdx.x;
  const int blk = blockIdx.x;
  const int b = blk / CH1;
  const int chunk = blk % CH1;
  const int t0 = chunk * TCHUNK;
  const int hh = tid >> 6;
  const int d = tid & 63;
  const float* Wk = Wpre + (hh * 192 + 64 + d) * 256;
  const float* Wv = Wpre + (hh * 192 + 128 + d) * 256;
  const float* xb = x + (size_t)b * (CC * TT);
  const int tl = tid & 31;
  const int cg = tid >> 5;

  float U[64];
#pragma unroll
  for (int i = 0; i < 64; ++i) U[i] = 0.f;
  float zacc = 0.f;

  for (int sub = 0; sub < NSUB; ++sub) {
    const int ts = t0 + sub * 32;
    // stage x[:, ts..ts+32) -> xs (coalesced 128B segments per half-wave)
#pragma unroll
    for (int j = 0; j < 32; ++j) {
      const int c = cg + 8 * j;
      xs[c * 32 + tl] = xb[(size_t)c * TT + ts + tl];
    }
    __syncthreads();

    // phase a: this thread's k row and v row over 32 t's
    float ak[32], av[32];
#pragma unroll
    for (int t = 0; t < 32; ++t) { ak[t] = 0.f; av[t] = 0.f; }
    for (int c4 = 0; c4 < 256; c4 += 4) {
      const float4 wk4 = *reinterpret_cast<const float4*>(Wk + c4);
      const float4 wv4 = *reinterpret_cast<const float4*>(Wv + c4);
#pragma unroll
      for (int j = 0; j < 4; ++j) {
        const float wk = reinterpret_cast<const float*>(&wk4)[j];
        const float wv = reinterpret_cast<const float*>(&wv4)[j];
        const float* xr = &xs[(c4 + j) * 32];
#pragma unroll
        for (int t4 = 0; t4 < 32; t4 += 4) {
          const float4 xv = *reinterpret_cast<const float4*>(xr + t4);
          ak[t4 + 0] += wk * xv.x; av[t4 + 0] += wv * xv.x;
          ak[t4 + 1] += wk * xv.y; av[t4 + 1] += wv * xv.y;
          ak[t4 + 2] += wk * xv.z; av[t4 + 2] += wv * xv.z;
          ak[t4 + 3] += wk * xv.w; av[t4 + 3] += wv * xv.w;
        }
      }
    }
    // publish v rows: vs[t][h*64+d] ; tid == h*64+d
#pragma unroll
    for (int t = 0; t < 32; ++t) vs[t * 256 + tid] = av[t];
    __syncthreads();

    // phase b: U[d][e] += exp(k[d,t]+EPS) * v[e,t] (vs reads are wave-broadcast)
#pragma unroll
    for (int t = 0; t < 32; ++t) {
      const float e = __expf(ak[t] + EPSF);
      zacc += e;
      const float* vr = &vs[t * 256 + hh * 64];
#pragma unroll
      for (int e4 = 0; e4 < 64; e4 += 4) {
        const float4 vv = *reinterpret_cast<const float4*>(vr + e4);
        U[e4 + 0] += e * vv.x;
        U[e4 + 1] += e * vv.y;
        U[e4 + 2] += e * vv.z;
        U[e4 + 3] += e * vv.w;
      }
    }
    __syncthreads();  // protect xs/vs before next sub-chunk restages
  }

  // write partials: Upart[blk][h][d][e], Zpart[blk][h*64+d]
  float* Up = ws + OFF_UPART + (size_t)blk * (HH * DD * DD) + tid * 64;
#pragma unroll
  for (int e4 = 0; e4 < 64; e4 += 4) {
    float4 o;
    o.x = U[e4 + 0]; o.y = U[e4 + 1]; o.z = U[e4 + 2]; o.w = U[e4 + 3];
    *reinterpret_cast<float4*>(Up + e4) = o;
  }
  ws[OFF_ZPART + blk * 256 + tid] = zacc;
}

// ---------------------------------------------------------------------------
// Kernel 2: reduce partials over the CH1 chunk-blocks of each batch,
// kv[b,h,d,e] = U/Z[d]. Grid 512 = (b,h) * 16 j-slices; 256 threads.
// ---------------------------------------------------------------------------
__global__ void k2_reduce_kv(float* __restrict__ ws) {
  const int bi = blockIdx.x;       // 0..511
  const int bh = bi >> 4;          // 0..31
  const int j = bi & 15;
  const int b = bh >> 2;
  const int hh = bh & 3;
  const int tid = threadIdx.x;

  __shared__ float zinv[64];
  if (tid < 64) {
    float z = 0.f;
    for (int cb = 0; cb < CH1; ++cb)
      z += ws[OFF_ZPART + (size_t)(b * CH1 + cb) * 256 + hh * 64 + tid];
    zinv[tid] = 1.0f / z;
  }
  __syncthreads();

  const int idx = j * 256 + tid;   // 0..4095 within (b,h)
  const int d = idx >> 6;
  float s = 0.f;
  for (int cb = 0; cb < CH1; ++cb)
    s += ws[OFF_UPART + (size_t)(b * CH1 + cb) * 16384 + hh * 4096 + idx];
  ws[OFF_KV + (size_t)(b * 4 + hh) * 4096 + idx] = s * zinv[d];
}

// ---------------------------------------------------------------------------
// Kernel 3a: P[b, h*64+e, c] = sum_d kv[b,h,d,e] * W_prenet[h*192+d, c]
// ---------------------------------------------------------------------------
__global__ void k3a_P(const float* __restrict__ Wpre, float* __restrict__ ws) {
  const int bi = blockIdx.x;       // b*256 + he
  const int b = bi >> 8;
  const int he = bi & 255;
  const int hh = he >> 6;
  const int e = he & 63;
  const int c = threadIdx.x;
  const float* kvp = ws + OFF_KV + (size_t)(b * 4 + hh) * 4096;
  float acc = 0.f;
#pragma unroll 8
  for (int d = 0; d < 64; ++d)
    acc += kvp[d * 64 + e] * Wpre[(size_t)(hh * 192 + d) * 256 + c];
  ws[OFF_P + (size_t)bi * 256 + c] = acc;
}

// ---------------------------------------------------------------------------
// Kernel 3b: M[b,o,c] = scale * sum_c2 W_proj[o,c2] * P[b,c2,c]
// ---------------------------------------------------------------------------
__global__ void k3b_M(const float* __restrict__ Wproj,
                      const float* __restrict__ scale, float* __restrict__ ws) {
  const int bi = blockIdx.x;       // b*256 + o
  const int b = bi >> 8;
  const int o = bi & 255;
  const int c = threadIdx.x;
  const float s = scale[0];
  const float* Pp = ws + OFF_P + (size_t)b * 65536;
  float acc = 0.f;
#pragma unroll 8
  for (int c2 = 0; c2 < 256; ++c2)
    acc += Wproj[(size_t)o * 256 + c2] * Pp[(size_t)c2 * 256 + c];
  ws[OFF_M + (size_t)bi * 256 + c] = s * acc;
}

// ---------------------------------------------------------------------------
// Kernel 4: out[b,:,t] = LN_C( M[b]@x[b,:,t] + scale*b_proj + x[b,:,t] )*gamma+beta
// One block per (b, 32-t chunk); thread o = tid computes row o for 32 t's.
// ---------------------------------------------------------------------------
__global__ __launch_bounds__(256, 4) void k4_proj_ln(
    const float* __restrict__ x, const float* __restrict__ bproj,
    const float* __restrict__ scale, const float* __restrict__ gamma,
    const float* __restrict__ beta, const float* __restrict__ ws,
    float* __restrict__ out) {
  __shared__ float xs[256 * 36];   // [c][t], stride 36 (pad: 4c+t bank pattern)
  __shared__ float red1[8 * 32], red2[8 * 32];
  __shared__ float mu[32], rs[32];

  const int blk = blockIdx.x;      // b*256 + chunk
  const int b = blk >> 8;
  const int chunk = blk & 255;
  const int t0 = chunk * 32;
  const int tid = threadIdx.x;
  const int tl = tid & 31;
  const float* xb = x + (size_t)b * (CC * TT);

  // stage x chunk
  {
    const int cg = tid >> 5;
#pragma unroll
    for (int j = 0; j < 32; ++j) {
      const int c = cg + 8 * j;
      xs[c * 36 + tl] = xb[(size_t)c * TT + t0 + tl];
    }
  }
  __syncthreads();

  // GEMM: y[o, 0..31] = sum_c M[b,o,c] * xs[c][:]
  float acc[32];
#pragma unroll
  for (int t = 0; t < 32; ++t) acc[t] = 0.f;
  const float* Mrow = ws + OFF_M + ((size_t)b * 256 + tid) * 256;
  for (int c4 = 0; c4 < 256; c4 += 4) {
    const float4 m4 = *reinterpret_cast<const float4*>(Mrow + c4);
#pragma unroll
    for (int j = 0; j < 4; ++j) {
      const float m = reinterpret_cast<const float*>(&m4)[j];
      const float* xr = &xs[(c4 + j) * 36];
#pragma unroll
      for (int t4 = 0; t4 < 32; t4 += 4) {
        const float4 xv = *reinterpret_cast<const float4*>(xr + t4);
        acc[t4 + 0] += m * xv.x;
        acc[t4 + 1] += m * xv.y;
        acc[t4 + 2] += m * xv.z;
        acc[t4 + 3] += m * xv.w;
      }
    }
  }
  __syncthreads();  // all xs reads done

  // residual + bias; write y back into xs row tid
  const float sb = scale[0] * bproj[tid];
  {
    float* xrow = &xs[tid * 36];
#pragma unroll
    for (int t4 = 0; t4 < 32; t4 += 4) {
      float4 xv = *reinterpret_cast<float4*>(xrow + t4);
      xv.x += acc[t4 + 0] + sb;
      xv.y += acc[t4 + 1] + sb;
      xv.z += acc[t4 + 2] + sb;
      xv.w += acc[t4 + 3] + sb;
      *reinterpret_cast<float4*>(xrow + t4) = xv;
    }
  }
  __syncthreads();

  // LN reduction over C: stage 1 (8 o-groups x 32 t)
  {
    const int og = tid >> 5;
    float s1 = 0.f, s2 = 0.f;
#pragma unroll
    for (int i = 0; i < 32; ++i) {
      const float v = xs[(og * 32 + i) * 36 + tl];
      s1 += v;
      s2 += v * v;
    }
    red1[og * 32 + tl] = s1;
    red2[og * 32 + tl] = s2;
  }
  __syncthreads();
  if (tid < 32) {
    float s1 = 0.f, s2 = 0.f;
#pragma unroll
    for (int og = 0; og < 8; ++og) {
      s1 += red1[og * 32 + tid];
      s2 += red2[og * 32 + tid];
    }
    const float m = s1 * (1.0f / 256.0f);
    const float var = s2 * (1.0f / 256.0f) - m * m;
    mu[tid] = m;
    rs[tid] = rsqrtf(var + EPSF);
  }
  __syncthreads();

  // normalize + affine + store (coalesced 128B segments)
  {
    float* ob = out + (size_t)b * (CC * TT) + t0;
    const int ow0 = tid >> 5;
#pragma unroll
    for (int it = 0; it < 32; ++it) {
      const int o = ow0 + 8 * it;
      const float v =
          (xs[o * 36 + tl] - mu[tl]) * rs[tl] * gamma[o] + beta[o];
      ob[(size_t)o * TT + tl] = v;
    }
  }
}

// ---------------------------------------------------------------------------
extern "C" void kernel_launch(void* const* d_in, const int* in_sizes, int n_in,
                              void* d_out, int out_size, void* d_ws,
                              size_t ws_size, hipStream_t stream) {
  (void)in_sizes; (void)n_in; (void)out_size; (void)ws_size;
  const float* x = (const float*)d_in[0];
  const float* Wpre = (const float*)d_in[1];
  const float* Wproj = (const float*)d_in[2];
  const float* bproj = (const float*)d_in[3];
  const float* scale = (const float*)d_in[4];
  const float* gamma = (const float*)d_in[5];
  const float* beta = (const float*)d_in[6];
  float* out = (float*)d_out;
  float* ws = (float*)d_ws;

  hipLaunchKernelGGL(k1_kv_partial, dim3(NB1), dim3(256), 0, stream, x, Wpre, ws);
  hipLaunchKernelGGL(k2_reduce_kv, dim3(512), dim3(256), 0, stream, ws);
  hipLaunchKernelGGL(k3a_P, dim3(BB * 256), dim3(256), 0, stream, Wpre, ws);
  hipLaunchKernelGGL(k3b_M, dim3(BB * 256), dim3(256), 0, stream, Wproj, scale, ws);
  hipLaunchKernelGGL(k4_proj_ln, dim3(BB * 256), dim3(256), 0, stream, x, bproj,
                     scale, gamma, beta, ws, out);
}

// Round 2
// 224.974 us; speedup vs baseline: 3.0460x; 3.0460x over previous
//
#include <hip/hip_runtime.h>
#include <hip/hip_bf16.h>
#include <math.h>

// Problem constants
#define BB 8
#define CC 256
#define TT 8192
#define EPSF 1e-5f

typedef short v8s __attribute__((ext_vector_type(8)));
typedef float v4f __attribute__((ext_vector_type(4)));

#define MFMA(a, b, c) __builtin_amdgcn_mfma_f32_16x16x32_bf16((a), (b), (c), 0, 0, 0)

// MFMA 16x16x32 bf16 fragment conventions (m89/m91 verified):
//   A[m][k]: m = lane&15, k = (lane>>4)*8 + j   (8 contiguous k per lane)
//   B[k][n]: n = lane&15, k = (lane>>4)*8 + j
//   C/D:     col = lane&15, row = (lane>>4)*4 + reg

// Workspace layout (float offsets); total ~20 MB (< the ~38 MB round-1 used OK)
#define OFF_WKV 0               // Wkv bf16 [h][type][64][256]  -> 131072 ushort
#define OFF_WPJ 65536           // Wproj bf16 [256][256]        -> 65536 ushort
#define OFF_UPART 98304         // fp32 [256 blk][4h][64][64]
#define OFF_ZPART 4292608       // fp32 [256 blk][256]
#define OFF_KV 4358144          // fp32 [b][h][64 d][64 e]
#define OFF_PT 4489216          // Pt bf16 [b][c][256 c2]       -> 524288 ushort
#define OFF_MBF 4751360         // M bf16 [b][o][c]             -> 524288 ushort

__device__ __forceinline__ unsigned short f2bf(float f) {
  __hip_bfloat16 h = __float2bfloat16(f);
  return __builtin_bit_cast(unsigned short, h);
}
__device__ __forceinline__ float bf2f(unsigned short u) {
  return __bfloat162float(__builtin_bit_cast(__hip_bfloat16, u));
}

// ---------------------------------------------------------------------------
// k0: pack weights to bf16. rows 0..511: Wkv[h][type][d][c]; rows 512..767: Wproj.
// ---------------------------------------------------------------------------
__global__ void k0_pack(const float* __restrict__ Wpre,
                        const float* __restrict__ Wproj,
                        float* __restrict__ ws) {
  const int r = blockIdx.x;
  const int c = threadIdx.x;
  if (r < 512) {
    const int h = r >> 7, type = (r >> 6) & 1, d = r & 63;
    const int src = h * 192 + 64 + type * 64 + d;
    ((unsigned short*)(ws + OFF_WKV))[r * 256 + c] = f2bf(Wpre[(size_t)src * 256 + c]);
  } else {
    const int rr = r - 512;
    ((unsigned short*)(ws + OFF_WPJ))[rr * 256 + c] = f2bf(Wproj[(size_t)rr * 256 + c]);
  }
}

// ---------------------------------------------------------------------------
// k1: per (b, 256-t chunk), 8 waves; wave = (head h = w>>1, type = w&1: 0=k,1=v).
// Per 64-t sub: stage x->LDS bf16 [t][c]; MFMA k/v rows; exp in fp32;
// stage e/v to LDS [row][t] (pitch 40); MFMA U += e @ v^T over two 32-t halves.
// Unnormalized softmax (shift-invariant; k std ~0.8 so no overflow), Z summed
// separately. Partials U,Z written per block for k2 to reduce.
// ---------------------------------------------------------------------------
__global__ __launch_bounds__(512, 2) void k1_kv(const float* __restrict__ x,
                                                float* __restrict__ ws) {
  // union: xs[64][264] ushort (16896) overlaid by per-head e/v buffers
  // (4 heads x (64x40 ek + 64x40 v) = 20480 ushorts = 40 KiB)
  __shared__ unsigned short lds[20480];

  const int tid = threadIdx.x;
  const int w = tid >> 6, lane = tid & 63, q = lane >> 4, cl = lane & 15;
  const int h = w >> 1, type = w & 1;
  const int bi = blockIdx.x;
  const int b = bi >> 5, chunk = bi & 31;
  const int t0 = chunk * 256;
  const float* xb = x + (size_t)b * (CC * TT);
  const unsigned short* wkv =
      (const unsigned short*)(ws + OFF_WKV) + (size_t)((h * 2 + type) * 64) * 256;
  unsigned short* ekb = &lds[h * 5120];         // ek[64][40]
  unsigned short* vbb = &lds[h * 5120 + 2560];  // v [64][40]

  v4f Uacc[2][4];
#pragma unroll
  for (int i = 0; i < 2; ++i)
#pragma unroll
    for (int j = 0; j < 4; ++j) Uacc[i][j] = (v4f){0.f, 0.f, 0.f, 0.f};
  float zacc[4][4];
#pragma unroll
  for (int i = 0; i < 4; ++i)
#pragma unroll
    for (int j = 0; j < 4; ++j) zacc[i][j] = 0.f;

  for (int sub = 0; sub < 4; ++sub) {
    const int ts = t0 + sub * 64;
    // ---- stage xs[t][c] (bf16, pitch 264; banks: c/2 -> 2-way = free) ----
    {
      const int c = tid & 255, th = tid >> 8;
      const float* xp = xb + (size_t)c * TT + ts + th * 32;
#pragma unroll
      for (int j = 0; j < 8; ++j) {
        const float4 v4 = reinterpret_cast<const float4*>(xp)[j];
        const int tb = th * 32 + j * 4;
        lds[(tb + 0) * 264 + c] = f2bf(v4.x);
        lds[(tb + 1) * 264 + c] = f2bf(v4.y);
        lds[(tb + 2) * 264 + c] = f2bf(v4.z);
        lds[(tb + 3) * 264 + c] = f2bf(v4.w);
      }
    }
    __syncthreads();

    // ---- phase A: rows = this wave's 64 k- or v-rows, cols = 64 t ----
    v4f acc[4][4];
#pragma unroll
    for (int i = 0; i < 4; ++i)
#pragma unroll
      for (int j = 0; j < 4; ++j) acc[i][j] = (v4f){0.f, 0.f, 0.f, 0.f};
#pragma unroll
    for (int ks = 0; ks < 8; ++ks) {
      v8s af[4], bfu[4];
#pragma unroll
      for (int rt = 0; rt < 4; ++rt)
        af[rt] = *(const v8s*)(wkv + (size_t)(rt * 16 + cl) * 256 + ks * 32 + q * 8);
#pragma unroll
      for (int ct = 0; ct < 4; ++ct)
        bfu[ct] = *(const v8s*)&lds[(ct * 16 + cl) * 264 + ks * 32 + q * 8];
#pragma unroll
      for (int rt = 0; rt < 4; ++rt)
#pragma unroll
        for (int ct = 0; ct < 4; ++ct)
          acc[rt][ct] = MFMA(af[rt], bfu[ct], acc[rt][ct]);
    }
    __syncthreads();  // all waves done with xs; e/v buffers overlay it

    // ---- phase B: two 32-t halves through LDS (pitch 40: 2-way max) ----
#pragma unroll
    for (int hp = 0; hp < 2; ++hp) {
      if (type == 0) {
#pragma unroll
        for (int rt = 0; rt < 4; ++rt)
#pragma unroll
          for (int cc = 0; cc < 2; ++cc) {
            const int ct = hp * 2 + cc;
#pragma unroll
            for (int reg = 0; reg < 4; ++reg) {
              const float e = __expf(acc[rt][ct][reg]);
              zacc[rt][reg] += e;
              ekb[(rt * 16 + q * 4 + reg) * 40 + cc * 16 + cl] = f2bf(e);
            }
          }
      } else {
#pragma unroll
        for (int rt = 0; rt < 4; ++rt)
#pragma unroll
          for (int cc = 0; cc < 2; ++cc) {
            const int ct = hp * 2 + cc;
#pragma unroll
            for (int reg = 0; reg < 4; ++reg)
              vbb[(rt * 16 + q * 4 + reg) * 40 + cc * 16 + cl] =
                  f2bf(acc[rt][ct][reg]);
          }
      }
      __syncthreads();  // head's wave pair exchanges e/v
      {
        const int du0 = type * 32;  // k-wave: U rows 0..31, v-wave: 32..63
        v8s afu[2], bfu[4];
#pragma unroll
        for (int ur = 0; ur < 2; ++ur)
          afu[ur] = *(const v8s*)&ekb[(du0 + ur * 16 + cl) * 40 + q * 8];
#pragma unroll
        for (int uc = 0; uc < 4; ++uc)
          bfu[uc] = *(const v8s*)&vbb[(uc * 16 + cl) * 40 + q * 8];
#pragma unroll
        for (int ur = 0; ur < 2; ++ur)
#pragma unroll
          for (int uc = 0; uc < 4; ++uc)
            Uacc[ur][uc] = MFMA(afu[ur], bfu[uc], Uacc[ur][uc]);
      }
      __syncthreads();  // half-1 / next sub will overwrite buffers
    }
  }

  // ---- Z: butterfly over the 16 col-lanes, store from cl==0 ----
  if (type == 0) {
#pragma unroll
    for (int m = 1; m < 16; m <<= 1)
#pragma unroll
      for (int rt = 0; rt < 4; ++rt)
#pragma unroll
        for (int reg = 0; reg < 4; ++reg)
          zacc[rt][reg] += __shfl_xor(zacc[rt][reg], m, 64);
    if (cl == 0) {
      for (int rt = 0; rt < 4; ++rt)
        for (int reg = 0; reg < 4; ++reg)
          ws[OFF_ZPART + (size_t)bi * 256 + h * 64 + rt * 16 + q * 4 + reg] =
              zacc[rt][reg];
    }
  }
  // ---- U partial store ----
  float* Up = ws + OFF_UPART + (size_t)bi * 16384 + h * 4096;
#pragma unroll
  for (int ur = 0; ur < 2; ++ur)
#pragma unroll
    for (int uc = 0; uc < 4; ++uc)
#pragma unroll
      for (int reg = 0; reg < 4; ++reg)
        Up[(type * 32 + ur * 16 + q * 4 + reg) * 64 + uc * 16 + cl] =
            Uacc[ur][uc][reg];
}

// ---------------------------------------------------------------------------
// k2: reduce 32 partial blocks per batch; kv = U / Z[d].
// ---------------------------------------------------------------------------
__global__ void k2_reduce_kv(float* __restrict__ ws) {
  const int bi = blockIdx.x;  // 0..511
  const int bh = bi >> 4, j = bi & 15;
  const int b = bh >> 2, h = bh & 3;
  const int tid = threadIdx.x;

  __shared__ float zinv[64];
  if (tid < 64) {
    float z = 0.f;
    for (int cb = 0; cb < 32; ++cb)
      z += ws[OFF_ZPART + (size_t)(b * 32 + cb) * 256 + h * 64 + tid];
    zinv[tid] = 1.0f / z;
  }
  __syncthreads();

  const int idx = j * 256 + tid;  // 0..4095 in (b,h)
  const int d = idx >> 6;
  float s = 0.f;
  for (int cb = 0; cb < 32; ++cb)
    s += ws[OFF_UPART + (size_t)(b * 32 + cb) * 16384 + h * 4096 + idx];
  ws[OFF_KV + (size_t)(b * 4 + h) * 4096 + idx] = s * zinv[d];
}

// ---------------------------------------------------------------------------
// k3a: P^T[b][c][h*64+e] = sum_d kv[b,h,d,e] * Wq[h*192+d][c]  (bf16, transposed
// so k3b's B-frags are contiguous along c2)
// ---------------------------------------------------------------------------
__global__ void k3a_P(const float* __restrict__ Wpre, float* __restrict__ ws) {
  const int bi = blockIdx.x;  // b*256 + he
  const int b = bi >> 8, he = bi & 255;
  const int h = he >> 6, e = he & 63;
  const int c = threadIdx.x;
  const float* kvp = ws + OFF_KV + (size_t)(b * 4 + h) * 4096;
  float acc = 0.f;
#pragma unroll 8
  for (int d = 0; d < 64; ++d)
    acc += kvp[d * 64 + e] * Wpre[(size_t)(h * 192 + d) * 256 + c];
  ((unsigned short*)(ws + OFF_PT))[(size_t)b * 65536 + (size_t)c * 256 + he] =
      f2bf(acc);
}

// ---------------------------------------------------------------------------
// k3b: M[b][o][c] = scale * (Wproj @ P)  via MFMA; grid = 8b x 4 c-groups.
// ---------------------------------------------------------------------------
__global__ __launch_bounds__(256, 2) void k3b_M(const float* __restrict__ scale,
                                                float* __restrict__ ws) {
  const int bi = blockIdx.x, b = bi >> 2, cg = bi & 3;
  const int tid = threadIdx.x, w = tid >> 6, lane = tid & 63, q = lane >> 4,
            cl = lane & 15;
  const unsigned short* wpj = (const unsigned short*)(ws + OFF_WPJ);
  const unsigned short* pt =
      (const unsigned short*)(ws + OFF_PT) + (size_t)b * 65536;
  v4f acc[4][4];
#pragma unroll
  for (int i = 0; i < 4; ++i)
#pragma unroll
    for (int j = 0; j < 4; ++j) acc[i][j] = (v4f){0.f, 0.f, 0.f, 0.f};
#pragma unroll
  for (int ks = 0; ks < 8; ++ks) {
    v8s af[4], bfu[4];
#pragma unroll
    for (int rt = 0; rt < 4; ++rt)
      af[rt] = *(const v8s*)(wpj + (size_t)(w * 64 + rt * 16 + cl) * 256 +
                             ks * 32 + q * 8);
#pragma unroll
    for (int ct = 0; ct < 4; ++ct)
      bfu[ct] = *(const v8s*)(pt + (size_t)(cg * 64 + ct * 16 + cl) * 256 +
                              ks * 32 + q * 8);
#pragma unroll
    for (int rt = 0; rt < 4; ++rt)
#pragma unroll
      for (int ct = 0; ct < 4; ++ct)
        acc[rt][ct] = MFMA(af[rt], bfu[ct], acc[rt][ct]);
  }
  const float s = scale[0];
  unsigned short* mbf = (unsigned short*)(ws + OFF_MBF);
#pragma unroll
  for (int rt = 0; rt < 4; ++rt)
#pragma unroll
    for (int ct = 0; ct < 4; ++ct)
#pragma unroll
      for (int reg = 0; reg < 4; ++reg) {
        const int o = w * 64 + rt * 16 + q * 4 + reg;
        const int c = cg * 64 + ct * 16 + cl;
        mbf[((size_t)b * 256 + o) * 256 + c] = f2bf(s * acc[rt][ct][reg]);
      }
}

// ---------------------------------------------------------------------------
// k4: out = LN_C( M@x + scale*b_proj + x ) * gamma + beta, MFMA + fused LN.
// Grid: 8b x 128 chunks of 64 t; 4 waves, wave w = rows w*64..w*64+63.
// ---------------------------------------------------------------------------
__global__ __launch_bounds__(256, 2) void k4_proj_ln(
    const float* __restrict__ x, const float* __restrict__ bproj,
    const float* __restrict__ scale, const float* __restrict__ gamma,
    const float* __restrict__ beta, const float* __restrict__ ws,
    float* __restrict__ out) {
  __shared__ unsigned short xs[64 * 264];
  __shared__ float red1[256], red2[256], muA[64], rsA[64];
  const int bi = blockIdx.x, b = bi >> 7, tc = bi & 127;
  const int tg0 = tc * 64;
  const int tid = threadIdx.x, w = tid >> 6, lane = tid & 63, q = lane >> 4,
            cl = lane & 15;
  const float* xb = x + (size_t)b * (CC * TT);

  // stage x[c][tg0..+64) -> xs[t][c] bf16
  {
    const int c = tid;
    const float* xp = xb + (size_t)c * TT + tg0;
#pragma unroll
    for (int j = 0; j < 16; ++j) {
      const float4 v4 = reinterpret_cast<const float4*>(xp)[j];
      const int tb = j * 4;
      xs[(tb + 0) * 264 + c] = f2bf(v4.x);
      xs[(tb + 1) * 264 + c] = f2bf(v4.y);
      xs[(tb + 2) * 264 + c] = f2bf(v4.z);
      xs[(tb + 3) * 264 + c] = f2bf(v4.w);
    }
  }
  __syncthreads();

  const unsigned short* mbf =
      (const unsigned short*)(ws + OFF_MBF) + (size_t)b * 65536;
  v4f acc[4][4];
#pragma unroll
  for (int i = 0; i < 4; ++i)
#pragma unroll
    for (int j = 0; j < 4; ++j) acc[i][j] = (v4f){0.f, 0.f, 0.f, 0.f};
#pragma unroll
  for (int ks = 0; ks < 8; ++ks) {
    v8s af[4], bfu[4];
#pragma unroll
    for (int rt = 0; rt < 4; ++rt)
      af[rt] = *(const v8s*)(mbf + (size_t)(w * 64 + rt * 16 + cl) * 256 +
                             ks * 32 + q * 8);
#pragma unroll
    for (int ct = 0; ct < 4; ++ct)
      bfu[ct] = *(const v8s*)&xs[(ct * 16 + cl) * 264 + ks * 32 + q * 8];
#pragma unroll
    for (int rt = 0; rt < 4; ++rt)
#pragma unroll
      for (int ct = 0; ct < 4; ++ct)
        acc[rt][ct] = MFMA(af[rt], bfu[ct], acc[rt][ct]);
  }

  // y = ctx_proj + scale*b_proj + residual (residual from bf16 xs)
  const float s = scale[0];
#pragma unroll
  for (int rt = 0; rt < 4; ++rt)
#pragma unroll
    for (int reg = 0; reg < 4; ++reg) {
      const int o = w * 64 + rt * 16 + q * 4 + reg;
      const float sb = s * bproj[o];
#pragma unroll
      for (int ct = 0; ct < 4; ++ct) {
        const int tl = ct * 16 + cl;
        acc[rt][ct][reg] += sb + bf2f(xs[tl * 264 + o]);
      }
    }

  // LN sums over C: per-lane 16 rows -> butterfly over q -> cross-wave LDS
#pragma unroll
  for (int ct = 0; ct < 4; ++ct) {
    float s1 = 0.f, s2 = 0.f;
#pragma unroll
    for (int rt = 0; rt < 4; ++rt)
#pragma unroll
      for (int reg = 0; reg < 4; ++reg) {
        const float v = acc[rt][ct][reg];
        s1 += v;
        s2 += v * v;
      }
    s1 += __shfl_xor(s1, 16, 64);
    s1 += __shfl_xor(s1, 32, 64);
    s2 += __shfl_xor(s2, 16, 64);
    s2 += __shfl_xor(s2, 32, 64);
    if (q == 0) {
      red1[w * 64 + ct * 16 + cl] = s1;
      red2[w * 64 + ct * 16 + cl] = s2;
    }
  }
  __syncthreads();
  if (tid < 64) {
    const float s1 = red1[tid] + red1[64 + tid] + red1[128 + tid] + red1[192 + tid];
    const float s2 = red2[tid] + red2[64 + tid] + red2[128 + tid] + red2[192 + tid];
    const float mu = s1 * (1.f / 256.f);
    const float var = s2 * (1.f / 256.f) - mu * mu;
    muA[tid] = mu;
    rsA[tid] = rsqrtf(var + EPSF);
  }
  __syncthreads();

  float* ob = out + (size_t)b * (CC * TT) + tg0;
#pragma unroll
  for (int rt = 0; rt < 4; ++rt)
#pragma unroll
    for (int reg = 0; reg < 4; ++reg) {
      const int o = w * 64 + rt * 16 + q * 4 + reg;
      const float g = gamma[o], bt = beta[o];
#pragma unroll
      for (int ct = 0; ct < 4; ++ct) {
        const int tl = ct * 16 + cl;
        ob[(size_t)o * TT + tl] = (acc[rt][ct][reg] - muA[tl]) * rsA[tl] * g + bt;
      }
    }
}

// ---------------------------------------------------------------------------
extern "C" void kernel_launch(void* const* d_in, const int* in_sizes, int n_in,
                              void* d_out, int out_size, void* d_ws,
                              size_t ws_size, hipStream_t stream) {
  (void)in_sizes; (void)n_in; (void)out_size; (void)ws_size;
  const float* x = (const float*)d_in[0];
  const float* Wpre = (const float*)d_in[1];
  const float* Wproj = (const float*)d_in[2];
  const float* bproj = (const float*)d_in[3];
  const float* scale = (const float*)d_in[4];
  const float* gamma = (const float*)d_in[5];
  const float* beta = (const float*)d_in[6];
  float* out = (float*)d_out;
  float* ws = (float*)d_ws;

  hipLaunchKernelGGL(k0_pack, dim3(768), dim3(256), 0, stream, Wpre, Wproj, ws);
  hipLaunchKernelGGL(k1_kv, dim3(256), dim3(512), 0, stream, x, ws);
  hipLaunchKernelGGL(k2_reduce_kv, dim3(512), dim3(256), 0, stream, ws);
  hipLaunchKernelGGL(k3a_P, dim3(BB * 256), dim3(256), 0, stream, Wpre, ws);
  hipLaunchKernelGGL(k3b_M, dim3(32), dim3(256), 0, stream, scale, ws);
  hipLaunchKernelGGL(k4_proj_ln, dim3(BB * 128), dim3(256), 0, stream, x, bproj,
                     scale, gamma, beta, ws, out);
}